// Round 9
// baseline (142.923 us; speedup 1.0000x reference)
//
#include <hip/hip_runtime.h>

// LSTM: B=65536 seqs, T=256, E=H=5, x in {0,1}. One thread per sequence.
// 1024 waves = 1 wave/SIMD. Issue model (validated R3/R5/R6/R7):
//   full-rate VALU 2 cyc; v_exp/v_rcp block issue 16 cyc + unhideable
//   latency tails at phase boundaries. R7: busy 711 + stall 405 = 1116.
// R9 = R8 retry with a FAST-MATH-ROBUST full-rate exp2:
//   R8's magic-number trick ((v+1.5*2^23)-1.5*2^23) was reassociated away
//   by the compiler -> u=0 -> 2^round(v) staircase -> absmax 0.27. Now:
//   n = rintf(v) (v_rndne_f32, opaque to reassociation), u = v-n exact,
//   deg-5 Taylor (rel err 2.4e-6), scale = bitcast((int(n)<<23)+0x3f800000)
//   via v_lshl_add_u32. All full-rate; only 6 pair-grouped v_rcp remain
//   transcendental. Inputs bounded: |gate| <= ~20, chat clamped +-60,
//   so int(n)+127 in [47,207] -- no exponent wrap.
// Math identical to R7 (passed, absmax 4.9e-4):
//   c' = [chat*Ai*Ag + 2log2e*(Eg-1)*Af]/(Ai*Af*Ag),  A* = 1+E*
//   h  = (Ec-1)/((1+Eo)(1+Ec));  chat = 2log2e*c;  rcp pair-grouped.
// Gate-pair layout: p0..7: row=(p>>1)*5+(p&1)*2+h ->
//   (i0,i1)(i2,i3)(f0,f1)(f2,f3)(g0,g1)(g2,g3)(o0,o1)(o2,o3)
//   p8:(i4,f4)=rows{4,9}; p9:(g4,o4)=rows{14,19}

typedef float v2f __attribute__((ext_vector_type(2)));

constexpr int TT = 256;

__device__ __forceinline__ float frcp(float v)  { return __builtin_amdgcn_rcpf(v); }

// ---- full-rate exp2, reassociation-immune ----
#define EXP2_C0 1.0f
#define EXP2_C1 6.931471805599453e-1f
#define EXP2_C2 2.402265069591007e-1f
#define EXP2_C3 5.550410866482158e-2f
#define EXP2_C4 9.618129107628477e-3f
#define EXP2_C5 1.3333558146428443e-3f

__device__ __forceinline__ float sexp2(float v) {
    float n = __builtin_rintf(v);        // v_rndne_f32 (full-rate)
    float u = v - n;                     // exact, in [-0.5, 0.5]
    int   ni = (int)n;                   // v_cvt_i32_f32 (exact on integers)
    float p = EXP2_C5;
    p = fmaf(p, u, EXP2_C4);
    p = fmaf(p, u, EXP2_C3);
    p = fmaf(p, u, EXP2_C2);
    p = fmaf(p, u, EXP2_C1);
    p = fmaf(p, u, EXP2_C0);
    unsigned sb = (((unsigned)ni) << 23) + 0x3f800000u;  // v_lshl_add_u32
    return p * __builtin_bit_cast(float, sb);
}

__device__ __forceinline__ v2f vexp2(v2f v) {
    float n0 = __builtin_rintf(v[0]);
    float n1 = __builtin_rintf(v[1]);
    v2f n; n[0] = n0; n[1] = n1;
    v2f u = v - n;                       // v_pk_add_f32
    int i0 = (int)n0, i1 = (int)n1;
    v2f p = {EXP2_C5, EXP2_C5};
    const v2f k4 = {EXP2_C4, EXP2_C4};
    const v2f k3 = {EXP2_C3, EXP2_C3};
    const v2f k2 = {EXP2_C2, EXP2_C2};
    const v2f k1 = {EXP2_C1, EXP2_C1};
    const v2f k0 = {EXP2_C0, EXP2_C0};
    p = __builtin_elementwise_fma(p, u, k4);   // v_pk_fma_f32 x5
    p = __builtin_elementwise_fma(p, u, k3);
    p = __builtin_elementwise_fma(p, u, k2);
    p = __builtin_elementwise_fma(p, u, k1);
    p = __builtin_elementwise_fma(p, u, k0);
    unsigned s0 = (((unsigned)i0) << 23) + 0x3f800000u;
    unsigned s1 = (((unsigned)i1) << 23) + 0x3f800000u;
    v2f s;
    s[0] = __builtin_bit_cast(float, s0);
    s[1] = __builtin_bit_cast(float, s1);
    return p * s;                        // v_pk_mul_f32
}

__device__ __forceinline__ int pair_row(int p, int h) {
    if (p < 8) return (p >> 1) * 5 + (p & 1) * 2 + h;
    return (p == 8) ? (h ? 9 : 4) : (h ? 19 : 14);
}

// pack two uniform floats into a uniform 64-bit value (SGPR pair residency)
__device__ __forceinline__ double upack(float w0, float w1) {
    unsigned lo = (unsigned)__builtin_amdgcn_readfirstlane(__builtin_bit_cast(int, w0));
    unsigned hi = (unsigned)__builtin_amdgcn_readfirstlane(__builtin_bit_cast(int, w1));
    unsigned long long u = ((unsigned long long)hi << 32) | lo;
    return __builtin_bit_cast(double, u);
}

__global__ __launch_bounds__(256)
__attribute__((amdgpu_waves_per_eu(1, 1)))
void lstm_fused(
    const int* __restrict__ x,       // [B, T]
    const float* __restrict__ emb,   // [2, E]
    const float* __restrict__ W_ih,  // [4H, E]
    const float* __restrict__ W_hh,  // [4H, H]
    const float* __restrict__ b_ih,  // [4H]
    const float* __restrict__ b_hh,  // [4H]
    const float* __restrict__ W_lin, // [2, H]
    const float* __restrict__ b_lin, // [2]
    float* __restrict__ out)         // [B, 2]
{
    const int b = blockIdx.x * blockDim.x + threadIdx.x;

    const float NL2E  = -1.4426950408889634f;  // -log2(e)   (sigmoid rows)
    const float T2L2E =  2.8853900817779268f;  // 2*log2(e)  (tanh rows)
    const v2f ONE = {1.f, 1.f};
    const v2f T2v = {T2L2E, T2L2E};
    const v2f CLp = {60.f, 60.f};
    const v2f CLn = {-60.f, -60.f};

    // ---- setup ----
    double wu[4][10];   // matvec weights k=0..3, uniform -> SGPR pairs
    v2f    wv[10];      // matvec weights k=4, pinned VGPR
    v2f bpk[10], dpk[10];
#pragma unroll
    for (int p = 0; p < 10; ++p) {
        float v0[2], v1[2], w4[2];
        float wk[4][2];
#pragma unroll
        for (int h = 0; h < 2; ++h) {
            const int r = pair_row(p, h);
            const float s = (r >= 10 && r < 15) ? T2L2E : NL2E;
            float g0 = b_ih[r] + b_hh[r], g1 = g0;
#pragma unroll
            for (int e = 0; e < 5; ++e) {
                float w = W_ih[r * 5 + e];
                g0 = fmaf(w, emb[e],     g0);
                g1 = fmaf(w, emb[5 + e], g1);
            }
            v0[h] = s * g0;
            v1[h] = s * (g1 - g0);
#pragma unroll
            for (int k = 0; k < 4; ++k) wk[k][h] = s * W_hh[r * 5 + k];
            w4[h] = s * W_hh[r * 5 + 4];
        }
#pragma unroll
        for (int k = 0; k < 4; ++k) wu[k][p] = upack(wk[k][0], wk[k][1]);
        asm volatile("" : "+v"(w4[0]), "+v"(w4[1]));
        wv[p][0] = w4[0]; wv[p][1] = w4[1];
        asm volatile("" : "+v"(v0[0]), "+v"(v0[1]), "+v"(v1[0]), "+v"(v1[1]));
        bpk[p][0] = v0[0]; bpk[p][1] = v0[1];
        dpk[p][0] = v1[0]; dpk[p][1] = v1[1];
    }

    v2f chat01 = {0.f, 0.f}, chat23 = {0.f, 0.f};
    float chat4 = 0.f;
    v2f h01 = {0.f, 0.f}, h23 = {0.f, 0.f};
    float h4 = 0.f;

    auto step = [&](int xt) {
        const float xtf = (float)xt;
        v2f xv; xv[0] = xtf; xv[1] = xtf;
        v2f g[10];
#pragma unroll
        for (int p = 0; p < 10; ++p)
            g[p] = __builtin_elementwise_fma(xv, dpk[p], bpk[p]);
        // ---- recurrent matvec: k=0..3 from SGPR pairs, k=4 from VGPR ----
        const float hk[4] = {h01[0], h01[1], h23[0], h23[1]};
#pragma unroll
        for (int k = 0; k < 4; ++k) {
            v2f hv; hv[0] = hk[k]; hv[1] = hk[k];
#pragma unroll
            for (int p = 0; p < 10; ++p) {
                v2f w = __builtin_bit_cast(v2f, wu[k][p]);
                g[p] = __builtin_elementwise_fma(w, hv, g[p]);
            }
        }
        {
            v2f hv; hv[0] = h4; hv[1] = h4;
#pragma unroll
            for (int p = 0; p < 10; ++p)
                g[p] = __builtin_elementwise_fma(wv[p], hv, g[p]);
        }

        // ---- all 20 gate exp2, full-rate (pipelined, no trans convoys) ----
        v2f E0 = vexp2(g[0]);   // Ei01
        v2f E1 = vexp2(g[1]);   // Ei23
        v2f E2 = vexp2(g[2]);   // Ef01
        v2f E3 = vexp2(g[3]);   // Ef23
        v2f E4 = vexp2(g[4]);   // Eg01
        v2f E5 = vexp2(g[5]);   // Eg23
        v2f E6 = vexp2(g[6]);   // Eo01
        v2f E7 = vexp2(g[7]);   // Eo23
        v2f E8 = vexp2(g[8]);   // (Ei4,Ef4)
        v2f E9 = vexp2(g[9]);   // (Eg4,Eo4)

        // ---- c-combine ----
        v2f Ai01 = E0 + ONE, Af01 = E2 + ONE, Ag01 = E4 + ONE;
        v2f P01 = Ai01 * Ag01, D01 = P01 * Af01;
        v2f t01 = __builtin_elementwise_fma(T2v, E4, -T2v);
        v2f N01 = __builtin_elementwise_fma(chat01, P01, t01 * Af01);

        v2f Ai23 = E1 + ONE, Af23 = E3 + ONE, Ag23 = E5 + ONE;
        v2f P23 = Ai23 * Ag23, D23 = P23 * Af23;
        v2f t23 = __builtin_elementwise_fma(T2v, E5, -T2v);
        v2f N23 = __builtin_elementwise_fma(chat23, P23, t23 * Af23);

        v2f AiAf4 = E8 + ONE;   // (Ai4, Af4)
        v2f AgAo4 = E9 + ONE;   // (Ag4, Ao4)
        float P4 = AiAf4[0] * AgAo4[0];
        float D4 = P4 * AiAf4[1];
        float t4 = fmaf(T2L2E, E9[0], -T2L2E);
        float N4 = fmaf(chat4, P4, t4 * AiAf4[1]);

        {   // paired reciprocals: chat = N/D via rcp(D0*D1)
            float R01 = frcp(D01[0] * D01[1]);
            float R23 = frcp(D23[0] * D23[1]);
            float R4g = frcp(D4);
            v2f Rv01; Rv01[0] = R01; Rv01[1] = R01;
            chat01 = (N01 * __builtin_shufflevector(D01, D01, 1, 0)) * Rv01;
            v2f Rv23; Rv23[0] = R23; Rv23[1] = R23;
            chat23 = (N23 * __builtin_shufflevector(D23, D23, 1, 0)) * Rv23;
            chat4 = N4 * R4g;
        }
        // guard the integer-exponent path (real |chat| <~ 35)
        chat01 = __builtin_elementwise_min(__builtin_elementwise_max(chat01, CLn), CLp);
        chat23 = __builtin_elementwise_min(__builtin_elementwise_max(chat23, CLn), CLp);
        chat4  = fminf(fmaxf(chat4, -60.f), 60.f);

        // ---- h-phase: h = (Ec-1)/((1+Eo)(1+Ec)), Ec full-rate ----
        v2f Ec01 = vexp2(chat01);
        v2f Ec23 = vexp2(chat23);
        float Ec4 = sexp2(chat4);

        v2f Dn01 = (E6 + ONE) * (Ec01 + ONE), Tn01 = Ec01 - ONE;
        v2f Dn23 = (E7 + ONE) * (Ec23 + ONE), Tn23 = Ec23 - ONE;
        float Dn4 = AgAo4[1] * (Ec4 + 1.f), Tn4 = Ec4 - 1.f;

        {
            float S01 = frcp(Dn01[0] * Dn01[1]);
            float S23 = frcp(Dn23[0] * Dn23[1]);
            float S4  = frcp(Dn4);
            v2f Sv01; Sv01[0] = S01; Sv01[1] = S01;
            h01 = (Tn01 * __builtin_shufflevector(Dn01, Dn01, 1, 0)) * Sv01;
            v2f Sv23; Sv23[0] = S23; Sv23[1] = S23;
            h23 = (Tn23 * __builtin_shufflevector(Dn23, Dn23, 1, 0)) * Sv23;
            h4 = Tn4 * S4;
        }
    };

    // ---- main scan: 64 int4 loads, prefetch-next, 4 steps per iter ----
    const int4* xr = reinterpret_cast<const int4*>(x + (size_t)b * TT);
    int4 cur = xr[0];
#pragma unroll 1
    for (int it = 0; it < TT / 4 - 1; ++it) {
        int4 nxt = xr[it + 1];
        step(cur.x); step(cur.y); step(cur.z); step(cur.w);
        cur = nxt;
    }
    step(cur.x); step(cur.y); step(cur.z); step(cur.w);

    // ---- linear head ----
    const float hfin[5] = {h01[0], h01[1], h23[0], h23[1], h4};
    float o0 = b_lin[0], o1 = b_lin[1];
#pragma unroll
    for (int j = 0; j < 5; ++j) {
        o0 = fmaf(W_lin[j],     hfin[j], o0);
        o1 = fmaf(W_lin[5 + j], hfin[j], o1);
    }
    reinterpret_cast<float2*>(out)[b] = make_float2(o0, o1);
}

extern "C" void kernel_launch(void* const* d_in, const int* in_sizes, int n_in,
                              void* d_out, int out_size, void* d_ws, size_t ws_size,
                              hipStream_t stream) {
    const int* x        = (const int*)d_in[0];
    const float* emb    = (const float*)d_in[1];
    const float* W_ih   = (const float*)d_in[2];
    const float* W_hh   = (const float*)d_in[3];
    const float* b_ih   = (const float*)d_in[4];
    const float* b_hh   = (const float*)d_in[5];
    const float* W_lin  = (const float*)d_in[6];
    const float* b_lin  = (const float*)d_in[7];
    float* out          = (float*)d_out;

    const int B = in_sizes[0] / TT;   // 65536
    const int block = 256;
    const int grid = B / block;       // 256 blocks -> 1024 waves -> 1/SIMD

    lstm_fused<<<grid, block, 0, stream>>>(x, emb, W_ih, W_hh, b_ih, b_hh,
                                           W_lin, b_lin, out);
}